// Round 1
// baseline (811.016 us; speedup 1.0000x reference)
//
#include <hip/hip_runtime.h>

typedef unsigned short u16;
typedef __attribute__((ext_vector_type(4))) float f32x4;
typedef __attribute__((ext_vector_type(8))) short bf16x8;
typedef __attribute__((ext_vector_type(4))) unsigned short u16x4;
typedef __attribute__((ext_vector_type(4))) float float4v;

#define N 8192

__device__ __forceinline__ float bf2f(u16 u){
  union { float f; unsigned int i; } v; v.i = ((unsigned int)u) << 16; return v.f;
}
__device__ __forceinline__ u16 f2bf(float f){
  union { float f; unsigned int i; } v; v.f = f;
  unsigned int r = v.i + 0x7fffu + ((v.i >> 16) & 1u);
  return (u16)(r >> 16);
}
__device__ __forceinline__ f32x4 mfma16(bf16x8 a, bf16x8 b, f32x4 c){
  return __builtin_amdgcn_mfma_f32_16x16x32_bf16(a, b, c, 0, 0, 0);
}

// ---------------- pack adj (int32 0/1) -> bitmask [N][1024B] ----------------
__global__ __launch_bounds__(256) void k_pack(const int* __restrict__ adj,
                                              unsigned long long* __restrict__ packed){
  const int wid = blockIdx.x * 4 + (threadIdx.x >> 6);
  const int lane = threadIdx.x & 63;
  const size_t base = (size_t)wid * 128;
  for (int g = 0; g < 128; ++g){
    const size_t grp = base + g;
    const int v = adj[grp * 64 + lane];
    const unsigned long long mask = __ballot(v != 0);
    if (lane == 0) packed[grp] = mask;
  }
}

// ---------------- split f32 -> bf16 hi/lo (row-major) ----------------
__global__ void k_split_x(const float* __restrict__ x, u16* __restrict__ hi, u16* __restrict__ lo){
  const int idx = blockIdx.x * 256 + threadIdx.x;   // over N*128/4
  float4v v = ((const float4v*)x)[idx];
  u16x4 h, l;
  #pragma unroll
  for (int e = 0; e < 4; ++e){ u16 hb = f2bf(v[e]); h[e] = hb; l[e] = f2bf(v[e] - bf2f(hb)); }
  ((u16x4*)hi)[idx] = h; ((u16x4*)lo)[idx] = l;
}

// ---------------- transpose f32 [K][Ncols] -> bf16 [Ncols][K] (opt split) ----------------
template<bool SPLIT>
__global__ void k_transpose(const float* __restrict__ src, u16* __restrict__ dhi,
                            u16* __restrict__ dlo, int K, int Ncols){
  const size_t boff = (size_t)blockIdx.y * K * Ncols;
  const int idx = blockIdx.x * 256 + threadIdx.x;
  if (idx >= K * Ncols) return;
  const int n = idx / K, k = idx % K;
  const float v = src[boff + (size_t)k * Ncols + n];
  const u16 h = f2bf(v);
  dhi[boff + idx] = h;
  if constexpr (SPLIT) dlo[boff + idx] = f2bf(v - bf2f(h));
}

// ---------------- GEMM: outT[c][i] = sum_k A[c][k]*B[i][k], split-bf16, + f1/f2 ----------------
__global__ __launch_bounds__(64) void k_gemm_at(
    const u16* __restrict__ Ahi, const u16* __restrict__ Alo,   // [heads][128][K]
    const u16* __restrict__ Bhi, const u16* __restrict__ Blo,   // [N][K]
    u16* __restrict__ outT,                                     // [heads][128][N]
    const float* __restrict__ avec,                             // [heads][256]
    float* __restrict__ f1, float* __restrict__ f2,             // [heads][N] (pre-zeroed)
    int K)
{
  const int head = blockIdx.z;
  Ahi += (size_t)head * 128 * K; Alo += (size_t)head * 128 * K;
  outT += (size_t)head * 128 * N;
  avec += (size_t)head * 256;
  f1 += (size_t)head * N; f2 += (size_t)head * N;
  const int lane = threadIdx.x & 63;
  const int r16 = lane & 15, g4 = lane >> 4;
  const int cg = blockIdx.y;
  const size_t ib = (size_t)blockIdx.x * 128;
  f32x4 acc[8];
  #pragma unroll
  for (int it = 0; it < 8; ++it) acc[it] = (f32x4){0.f, 0.f, 0.f, 0.f};
  for (int kk = 0; kk < K; kk += 32){
    bf16x8 ah = *(const bf16x8*)(Ahi + (size_t)(cg * 16 + r16) * K + kk + g4 * 8);
    bf16x8 al = *(const bf16x8*)(Alo + (size_t)(cg * 16 + r16) * K + kk + g4 * 8);
    #pragma unroll
    for (int it = 0; it < 8; ++it){
      const size_t boff = (ib + it * 16 + r16) * (size_t)K + kk + g4 * 8;
      bf16x8 bh = *(const bf16x8*)(Bhi + boff);
      bf16x8 bl = *(const bf16x8*)(Blo + boff);
      acc[it] = mfma16(ah, bh, acc[it]);
      acc[it] = mfma16(ah, bl, acc[it]);
      acc[it] = mfma16(al, bh, acc[it]);
    }
  }
  float a1v[4], a2v[4];
  #pragma unroll
  for (int q = 0; q < 4; ++q){
    a1v[q] = avec[cg * 16 + g4 * 4 + q];
    a2v[q] = avec[128 + cg * 16 + g4 * 4 + q];
  }
  #pragma unroll
  for (int it = 0; it < 8; ++it){
    float p1 = 0.f, p2 = 0.f;
    #pragma unroll
    for (int q = 0; q < 4; ++q){
      float v = acc[it][q];
      outT[(size_t)(cg * 16 + g4 * 4 + q) * N + ib + it * 16 + r16] = f2bf(v);
      p1 += v * a1v[q]; p2 += v * a2v[q];
    }
    p1 += __shfl_xor(p1, 16); p1 += __shfl_xor(p1, 32);
    p2 += __shfl_xor(p2, 16); p2 += __shfl_xor(p2, 32);
    if (lane < 16){
      atomicAdd(&f1[ib + it * 16 + lane], p1);
      atomicAdd(&f2[ib + it * 16 + lane], p2);
    }
  }
}

// ---------------- fused masked-softmax attention (flash-style, rank-1 scores) ----------------
// block = 4 waves = 4 j-segments of the same rows; LDS merge at end.
template<int RG, bool L2OUT>
__global__ __launch_bounds__(256) void k_attn(
    const unsigned char* __restrict__ pk,      // packed bits [N][1024]
    const u16* __restrict__ whT_all,           // [H][128][N] bf16
    const float* __restrict__ f1_all, const float* __restrict__ f2_all,
    u16* __restrict__ out_hi, u16* __restrict__ out_lo,   // layer1: [N][256] at col h*128
    float* __restrict__ out_f32, u16* __restrict__ comb)  // layer2: d_out node + combined
{
  constexpr int ROWS = RG * 16;
  __shared__ float smO[3][ROWS][132];
  __shared__ float smM[3][ROWS];
  __shared__ float smL[3][ROWS];

  const int h = blockIdx.y;
  const u16* whT = whT_all + (size_t)h * 128 * N;
  const float* f1 = f1_all + (size_t)h * N;
  const float* f2 = f2_all + (size_t)h * N;
  const int seg = threadIdx.x >> 6;
  const int lane = threadIdx.x & 63;
  const int r16 = lane & 15, g4 = lane >> 4;
  const size_t ibase = (size_t)blockIdx.x * ROWS;

  float m[RG], l[RG], f1v[RG];
  f32x4 acc[RG][8];
  #pragma unroll
  for (int rg = 0; rg < RG; ++rg){
    m[rg] = -3e38f; l[rg] = 0.f;
    f1v[rg] = f1[ibase + rg * 16 + r16];
    #pragma unroll
    for (int ct = 0; ct < 8; ++ct) acc[rg][ct] = (f32x4){0.f, 0.f, 0.f, 0.f};
  }

  for (int t = seg; t < 128; t += 4){
    const int j0 = t * 64;
    // B fragments: Wh[j][c] = whT[c][j], 16B contiguous per lane
    bf16x8 bfr[2][8];
    #pragma unroll
    for (int kk = 0; kk < 2; ++kk)
      #pragma unroll
      for (int ct = 0; ct < 8; ++ct)
        bfr[kk][ct] = *(const bf16x8*)(whT + (size_t)(ct * 16 + r16) * N + j0 + kk * 32 + g4 * 8);
    // f2 for this lane's 16 j's
    float4v f2a = *(const float4v*)(f2 + j0 + g4 * 8);
    float4v f2b = *(const float4v*)(f2 + j0 + g4 * 8 + 4);
    float4v f2c = *(const float4v*)(f2 + j0 + 32 + g4 * 8);
    float4v f2d = *(const float4v*)(f2 + j0 + 32 + g4 * 8 + 4);
    float f2v[16] = {f2a[0],f2a[1],f2a[2],f2a[3], f2b[0],f2b[1],f2b[2],f2b[3],
                     f2c[0],f2c[1],f2c[2],f2c[3], f2d[0],f2d[1],f2d[2],f2d[3]};
    // adjacency bits
    unsigned int bits[RG][2];
    #pragma unroll
    for (int rg = 0; rg < RG; ++rg){
      const size_t rb = (ibase + rg * 16 + r16) * 1024 + (j0 >> 3);
      bits[rg][0] = pk[rb + g4];
      bits[rg][1] = pk[rb + 4 + g4];
    }
    #pragma unroll
    for (int rg = 0; rg < RG; ++rg){
      float e[16]; float tmax = -3e38f;
      #pragma unroll
      for (int kk = 0; kk < 2; ++kk)
        #pragma unroll
        for (int x = 0; x < 8; ++x){
          float s = f1v[rg] + f2v[kk * 8 + x];
          s = (s > 0.f) ? s : 0.2f * s;                 // leaky relu
          s = ((bits[rg][kk] >> x) & 1u) ? s : -3e38f;  // mask
          e[kk * 8 + x] = s; tmax = fmaxf(tmax, s);
        }
      tmax = fmaxf(tmax, __shfl_xor(tmax, 16));
      tmax = fmaxf(tmax, __shfl_xor(tmax, 32));
      const float mold = m[rg];
      const float mnew = fmaxf(mold, tmax);
      m[rg] = mnew;
      float psum = 0.f;
      u16 pb[16];
      #pragma unroll
      for (int kk = 0; kk < 2; ++kk)
        #pragma unroll
        for (int x = 0; x < 8; ++x){
          float p = ((bits[rg][kk] >> x) & 1u) ? __expf(e[kk * 8 + x] - mnew) : 0.f;
          psum += p;
          pb[kk * 8 + x] = f2bf(p);
        }
      psum += __shfl_xor(psum, 16);
      psum += __shfl_xor(psum, 32);
      const float sc = __expf(mold - mnew);
      l[rg] = l[rg] * sc + psum;
      if (__any(mnew != mold)){
        float s0 = __shfl(sc, g4 * 4 + 0), s1 = __shfl(sc, g4 * 4 + 1);
        float s2 = __shfl(sc, g4 * 4 + 2), s3 = __shfl(sc, g4 * 4 + 3);
        f32x4 sv = {s0, s1, s2, s3};
        #pragma unroll
        for (int ct = 0; ct < 8; ++ct) acc[rg][ct] *= sv;
      }
      bf16x8 a0, a1;
      #pragma unroll
      for (int x = 0; x < 8; ++x){ a0[x] = (short)pb[x]; a1[x] = (short)pb[8 + x]; }
      #pragma unroll
      for (int ct = 0; ct < 8; ++ct){
        acc[rg][ct] = mfma16(a0, bfr[0][ct], acc[rg][ct]);
        acc[rg][ct] = mfma16(a1, bfr[1][ct], acc[rg][ct]);
      }
    }
  }
  // ---- merge 4 segments in LDS ----
  if (seg > 0){
    #pragma unroll
    for (int rg = 0; rg < RG; ++rg){
      #pragma unroll
      for (int ct = 0; ct < 8; ++ct)
        #pragma unroll
        for (int q = 0; q < 4; ++q)
          smO[seg - 1][rg * 16 + g4 * 4 + q][ct * 16 + r16] = acc[rg][ct][q];
      if (lane < 16){ smM[seg - 1][rg * 16 + lane] = m[rg]; smL[seg - 1][rg * 16 + lane] = l[rg]; }
    }
  }
  __syncthreads();
  if (seg == 0){
    #pragma unroll
    for (int rg = 0; rg < RG; ++rg){
      #pragma unroll
      for (int q = 0; q < 4; ++q){
        const int r = rg * 16 + g4 * 4 + q;
        const float m0 = __shfl(m[rg], g4 * 4 + q);
        const float l0 = __shfl(l[rg], g4 * 4 + q);
        const float mm = fmaxf(fmaxf(m0, smM[0][r]), fmaxf(smM[1][r], smM[2][r]));
        const float w0 = __expf(m0 - mm);
        const float w1 = __expf(smM[0][r] - mm);
        const float w2 = __expf(smM[1][r] - mm);
        const float w3 = __expf(smM[2][r] - mm);
        const float L = w0 * l0 + w1 * smL[0][r] + w2 * smL[1][r] + w3 * smL[2][r];
        const float rinv = 1.f / L;
        #pragma unroll
        for (int ct = 0; ct < 8; ++ct){
          const int c = ct * 16 + r16;
          float val = w0 * acc[rg][ct][q] + w1 * smO[0][r][c] + w2 * smO[1][r][c] + w3 * smO[2][r][c];
          float o = val * rinv;
          o = (o > 0.f) ? o : (__expf(o) - 1.f);   // elu
          const size_t i = ibase + r;
          if constexpr (!L2OUT){
            const u16 hb = f2bf(o);
            out_hi[i * 256 + (size_t)h * 128 + c] = hb;
            out_lo[i * 256 + (size_t)h * 128 + c] = f2bf(o - bf2f(hb));
          } else {
            out_f32[i * 128 + c] = o;
            comb[i * 256 + 128 + c] = f2bf(o);
          }
        }
      }
    }
  }
}

// ---------------- copy x (f32) into combined[:, :128] as bf16 ----------------
__global__ void k_copyx(const float* __restrict__ x, u16* __restrict__ comb){
  const int idx = blockIdx.x * 256 + threadIdx.x;  // over N*128/4
  const int i = idx >> 5;
  const int c4 = (idx & 31) * 4;
  float4v v = *(const float4v*)(x + (size_t)i * 128 + c4);
  u16x4 hv;
  #pragma unroll
  for (int e = 0; e < 4; ++e) hv[e] = f2bf(v[e]);
  *(u16x4*)(comb + (size_t)i * 256 + c4) = hv;
}

// ---------------- row-major GEMM + bias + relu (+optional column-sum) ----------------
template<bool STORE, bool COLSUM>
__global__ __launch_bounds__(256) void k_gemm_row(
    const u16* __restrict__ A,   // [M][K] bf16
    const u16* __restrict__ BT,  // [Ntot][K] bf16
    const float* __restrict__ bias,
    u16* __restrict__ out, float* __restrict__ csum,
    int K, int Ntot)
{
  const int lane = threadIdx.x & 63, w = threadIdx.x >> 6;
  const int r16 = lane & 15, g4 = lane >> 4;
  const size_t rbase = (size_t)blockIdx.x * 64 + w * 16;
  const int cbase = blockIdx.y * 128;
  f32x4 acc[8];
  #pragma unroll
  for (int ct = 0; ct < 8; ++ct) acc[ct] = (f32x4){0.f, 0.f, 0.f, 0.f};
  for (int kk = 0; kk < K; kk += 32){
    bf16x8 af = *(const bf16x8*)(A + (rbase + r16) * (size_t)K + kk + g4 * 8);
    #pragma unroll
    for (int ct = 0; ct < 8; ++ct){
      bf16x8 bfr = *(const bf16x8*)(BT + (size_t)(cbase + ct * 16 + r16) * K + kk + g4 * 8);
      acc[ct] = mfma16(af, bfr, acc[ct]);
    }
  }
  #pragma unroll
  for (int ct = 0; ct < 8; ++ct){
    const float bv = bias[cbase + ct * 16 + r16];
    float s = 0.f;
    #pragma unroll
    for (int q = 0; q < 4; ++q){
      float v = acc[ct][q] + bv;
      v = fmaxf(v, 0.f);
      if constexpr (STORE)
        out[(rbase + g4 * 4 + q) * (size_t)Ntot + cbase + ct * 16 + r16] = f2bf(v);
      s += v;
    }
    if constexpr (COLSUM){
      s += __shfl_xor(s, 16); s += __shfl_xor(s, 32);
      if (lane < 16) atomicAdd(&csum[cbase + ct * 16 + lane], s);
    }
  }
}

__global__ void k_final(const float* __restrict__ csum, float* __restrict__ out){
  out[threadIdx.x] = csum[threadIdx.x] * (1.f / 8192.f);
}

// ---------------- host launch ----------------
extern "C" void kernel_launch(void* const* d_in, const int* in_sizes, int n_in,
                              void* d_out, int out_size, void* d_ws, size_t ws_size,
                              hipStream_t stream) {
  const int*   adj = (const int*)d_in[0];
  const float* x   = (const float*)d_in[1];
  const float* Wh  = (const float*)d_in[2];
  const float* ah  = (const float*)d_in[3];
  const float* Wo  = (const float*)d_in[4];
  const float* ao  = (const float*)d_in[5];
  const float* g1  = (const float*)d_in[6];
  const float* b1  = (const float*)d_in[7];
  const float* g2  = (const float*)d_in[8];
  const float* b2  = (const float*)d_in[9];
  float* outp = (float*)d_out;
  char* ws = (char*)d_ws;

  // workspace layout (bytes)
  const size_t PK   = 0;          // 8,388,608  (packed adj)  [H1 aliases later]
  const size_t WHT1 = 8388608;    // 4,194,304  (WhT heads)   [COMB aliases later]
  const size_t FV   = 12582912;   // 196,608    (F1A,F2A,F1B,F2B)
  const size_t F1A  = FV;
  const size_t F2A  = FV + 65536;
  const size_t F1B  = FV + 131072;
  const size_t F2B  = FV + 163840;
  const size_t HHI  = 12779520;   // 4,194,304
  const size_t HLO  = 16973824;   // 4,194,304
  const size_t WHT2 = 21168128;   // 2,097,152
  const size_t XHI  = 23265280;   // 2,097,152
  const size_t XLO  = 25362432;   // 2,097,152
  const size_t CSUM = 27459584;   // 512
  const size_t WTHH = 27460096;   // 65,536
  const size_t WTHL = 27525632;   // 65,536
  const size_t WOTH = 27591168;   // 65,536
  const size_t WOTL = 27656704;   // 65,536
  const size_t G1T  = 27722240;   // 131,072
  const size_t G2T  = 27853312;   // 65,536
  const size_t H1   = PK;         // alias (packed dead by then)
  const size_t COMB = WHT1;       // alias (WhT1 dead by then)

  hipMemsetAsync(ws + FV, 0, 196608, stream);
  hipMemsetAsync(ws + CSUM, 0, 512, stream);

  k_pack<<<2048, 256, 0, stream>>>(adj, (unsigned long long*)(ws + PK));
  k_split_x<<<1024, 256, 0, stream>>>(x, (u16*)(ws + XHI), (u16*)(ws + XLO));
  k_transpose<true ><<<dim3(64, 2), 256, 0, stream>>>(Wh, (u16*)(ws + WTHH), (u16*)(ws + WTHL), 128, 128);
  k_transpose<true ><<<dim3(128, 1), 256, 0, stream>>>(Wo, (u16*)(ws + WOTH), (u16*)(ws + WOTL), 256, 128);
  k_transpose<false><<<dim3(256, 1), 256, 0, stream>>>(g1, (u16*)(ws + G1T), nullptr, 256, 256);
  k_transpose<false><<<dim3(128, 1), 256, 0, stream>>>(g2, (u16*)(ws + G2T), nullptr, 256, 128);

  // layer-1 Wh GEMM (split-bf16, exact-ish) + f1/f2
  k_gemm_at<<<dim3(64, 8, 2), 64, 0, stream>>>(
      (const u16*)(ws + WTHH), (const u16*)(ws + WTHL),
      (const u16*)(ws + XHI),  (const u16*)(ws + XLO),
      (u16*)(ws + WHT1), ah, (float*)(ws + F1A), (float*)(ws + F2A), 128);

  // layer-1 attention (2 heads), writes h split hi/lo
  k_attn<2, false><<<dim3(256, 2), 256, 0, stream>>>(
      (const unsigned char*)(ws + PK), (const u16*)(ws + WHT1),
      (const float*)(ws + F1A), (const float*)(ws + F2A),
      (u16*)(ws + HHI), (u16*)(ws + HLO), nullptr, nullptr);

  // layer-2 Wh GEMM
  k_gemm_at<<<dim3(64, 8, 1), 64, 0, stream>>>(
      (const u16*)(ws + WOTH), (const u16*)(ws + WOTL),
      (const u16*)(ws + HHI),  (const u16*)(ws + HLO),
      (u16*)(ws + WHT2), ao, (float*)(ws + F1B), (float*)(ws + F2B), 256);

  k_copyx<<<1024, 256, 0, stream>>>(x, (u16*)(ws + COMB));

  // layer-2 attention -> node_emb (f32 to d_out) + combined[:,128:]
  k_attn<1, true><<<dim3(512, 1), 256, 0, stream>>>(
      (const unsigned char*)(ws + PK), (const u16*)(ws + WHT2),
      (const float*)(ws + F1B), (const float*)(ws + F2B),
      nullptr, nullptr, outp, (u16*)(ws + COMB));

  // readout MLP
  k_gemm_row<true, false><<<dim3(128, 2), 256, 0, stream>>>(
      (const u16*)(ws + COMB), (const u16*)(ws + G1T), b1,
      (u16*)(ws + H1), nullptr, 256, 256);
  k_gemm_row<false, true><<<dim3(128, 1), 256, 0, stream>>>(
      (const u16*)(ws + H1), (const u16*)(ws + G2T), b2,
      nullptr, (float*)(ws + CSUM), 256, 128);
  k_final<<<1, 128, 0, stream>>>((const float*)(ws + CSUM), outp + (size_t)N * 128);
}

// Round 2
// 768.256 us; speedup vs baseline: 1.0557x; 1.0557x over previous
//
#include <hip/hip_runtime.h>
#include <hip/hip_bf16.h>

typedef unsigned short u16;
typedef __attribute__((ext_vector_type(4))) float f32x4;
typedef __attribute__((ext_vector_type(8))) short bf16x8;
typedef __attribute__((ext_vector_type(4))) unsigned short u16x4;

#define N 8192
#define LOG2E 1.4426950408889634f

__device__ __forceinline__ float bf2f(u16 u){
  union { float f; unsigned int i; } v; v.i = ((unsigned int)u) << 16; return v.f;
}
__device__ __forceinline__ u16 f2bf(float f){
  union { float f; unsigned int i; } v; v.f = f;
  unsigned int r = v.i + 0x7fffu + ((v.i >> 16) & 1u);
  return (u16)(r >> 16);
}
__device__ __forceinline__ f32x4 mfma16(bf16x8 a, bf16x8 b, f32x4 c){
  return __builtin_amdgcn_mfma_f32_16x16x32_bf16(a, b, c, 0, 0, 0);
}

// ---------------- pack adj (int32 0/1) -> bitmask [N][1024B] ----------------
__global__ __launch_bounds__(256) void k_pack(const int* __restrict__ adj,
                                              unsigned long long* __restrict__ packed){
  const int wid = blockIdx.x * 4 + (threadIdx.x >> 6);
  const int lane = threadIdx.x & 63;
  const size_t base = (size_t)wid * 128;
  #pragma unroll 4
  for (int g = 0; g < 128; ++g){
    const size_t grp = base + g;
    const int v = adj[grp * 64 + lane];
    const unsigned long long mask = __ballot(v != 0);
    if (lane == 0) packed[grp] = mask;
  }
}

// ---------------- x f32 -> bf16 (xbf) + combined[:, :128] ----------------
__global__ __launch_bounds__(256) void k_x2bf(const float* __restrict__ x,
                                              u16* __restrict__ xbf, u16* __restrict__ comb){
  const int idx = blockIdx.x * 256 + threadIdx.x;   // over N*128/4
  f32x4 v = ((const f32x4*)x)[idx];
  u16x4 h;
  #pragma unroll
  for (int e = 0; e < 4; ++e) h[e] = f2bf(v[e]);
  ((u16x4*)xbf)[idx] = h;
  const int i = idx >> 5, c4 = (idx & 31) * 4;
  *(u16x4*)(comb + (size_t)i * 256 + c4) = h;
}

// ---------------- transpose f32 [K][Ncols] -> bf16 [Ncols][K] ----------------
__global__ void k_transpose(const float* __restrict__ src, u16* __restrict__ dst,
                            int K, int Ncols){
  const size_t boff = (size_t)blockIdx.y * K * Ncols;
  const int idx = blockIdx.x * 256 + threadIdx.x;
  if (idx >= K * Ncols) return;
  const int n = idx / K, k = idx % K;
  dst[boff + idx] = f2bf(src[boff + (size_t)k * Ncols + n]);
}

// ---------------- wa vectors: wa1/wa2 = W@a halves (per head), wao1/wao2 ----------------
__global__ __launch_bounds__(256) void k_wa(const float* __restrict__ Wh, const float* __restrict__ ah,
                                            const float* __restrict__ Wo, const float* __restrict__ ao,
                                            float* __restrict__ wa){
  const int z = blockIdx.x, t = threadIdx.x;
  if (z < 2){
    if (t < 128){
      float a1 = 0.f, a2 = 0.f;
      for (int c = 0; c < 128; ++c){
        const float w = Wh[(size_t)z * 16384 + t * 128 + c];
        a1 += w * ah[z * 256 + c];
        a2 += w * ah[z * 256 + 128 + c];
      }
      wa[z * 128 + t] = a1; wa[256 + z * 128 + t] = a2;
    }
  } else {
    if (t < 256){
      float a1 = 0.f, a2 = 0.f;
      for (int c = 0; c < 128; ++c){
        const float w = Wo[(size_t)t * 128 + c];
        a1 += w * ao[c];
        a2 += w * ao[128 + c];
      }
      wa[512 + t] = a1; wa[768 + t] = a2;
    }
  }
}

// ---------------- gemv layer1: f1s/f2s = (x @ wa) * log2e ----------------
__global__ __launch_bounds__(256) void k_gemv1(const float* __restrict__ x, const float* __restrict__ wa,
                                               float* __restrict__ f1s, float* __restrict__ f2s){
  const int h = blockIdx.y;
  const float* wa1 = wa + h * 128;
  const float* wa2 = wa + 256 + h * 128;
  const int lane = threadIdx.x & 63, w = threadIdx.x >> 6;
  const int r16 = lane & 15, g4 = lane >> 4;
  const int row = blockIdx.x * 16 + w * 4 + g4;
  const float* xr = x + (size_t)row * 128 + r16 * 8;
  f32x4 x0 = *(const f32x4*)(xr);
  f32x4 x1 = *(const f32x4*)(xr + 4);
  f32x4 wA0 = *(const f32x4*)(wa1 + r16 * 8);
  f32x4 wA1 = *(const f32x4*)(wa1 + r16 * 8 + 4);
  f32x4 wB0 = *(const f32x4*)(wa2 + r16 * 8);
  f32x4 wB1 = *(const f32x4*)(wa2 + r16 * 8 + 4);
  float d1 = 0.f, d2 = 0.f;
  #pragma unroll
  for (int e = 0; e < 4; ++e){
    d1 += x0[e] * wA0[e] + x1[e] * wA1[e];
    d2 += x0[e] * wB0[e] + x1[e] * wB1[e];
  }
  d1 += __shfl_xor(d1, 1); d1 += __shfl_xor(d1, 2); d1 += __shfl_xor(d1, 4); d1 += __shfl_xor(d1, 8);
  d2 += __shfl_xor(d2, 1); d2 += __shfl_xor(d2, 2); d2 += __shfl_xor(d2, 4); d2 += __shfl_xor(d2, 8);
  if (r16 == 0){
    f1s[(size_t)h * N + row] = d1 * LOG2E;
    f2s[(size_t)h * N + row] = d2 * LOG2E;
  }
}

// ---------------- gemv layer2: f from h bf16 [N][256] ----------------
__global__ __launch_bounds__(256) void k_gemv2(const u16* __restrict__ hbf,
                                               const float* __restrict__ wao1, const float* __restrict__ wao2,
                                               float* __restrict__ f1s, float* __restrict__ f2s){
  const int lane = threadIdx.x & 63, w = threadIdx.x >> 6;
  const int r16 = lane & 15, g4 = lane >> 4;
  const int row = blockIdx.x * 16 + w * 4 + g4;
  bf16x8 h0 = *(const bf16x8*)(hbf + (size_t)row * 256 + r16 * 16);
  bf16x8 h1 = *(const bf16x8*)(hbf + (size_t)row * 256 + r16 * 16 + 8);
  float d1 = 0.f, d2 = 0.f;
  #pragma unroll
  for (int e = 0; e < 8; ++e){
    const float v0 = bf2f((u16)h0[e]), v1 = bf2f((u16)h1[e]);
    d1 += v0 * wao1[r16 * 16 + e] + v1 * wao1[r16 * 16 + 8 + e];
    d2 += v0 * wao2[r16 * 16 + e] + v1 * wao2[r16 * 16 + 8 + e];
  }
  d1 += __shfl_xor(d1, 1); d1 += __shfl_xor(d1, 2); d1 += __shfl_xor(d1, 4); d1 += __shfl_xor(d1, 8);
  d2 += __shfl_xor(d2, 1); d2 += __shfl_xor(d2, 2); d2 += __shfl_xor(d2, 4); d2 += __shfl_xor(d2, 8);
  if (r16 == 0){
    f1s[row] = d1 * LOG2E;
    f2s[row] = d2 * LOG2E;
  }
}

// ---------------- max over f2s per head ----------------
__global__ __launch_bounds__(256) void k_fmax(const float* __restrict__ f2s, float* __restrict__ fmax){
  const int h = blockIdx.x;
  const float* f = f2s + (size_t)h * N;
  float m = -3e38f;
  for (int i = threadIdx.x; i < N; i += 256) m = fmaxf(m, f[i]);
  m = fmaxf(m, __shfl_xor(m, 1));  m = fmaxf(m, __shfl_xor(m, 2));
  m = fmaxf(m, __shfl_xor(m, 4));  m = fmaxf(m, __shfl_xor(m, 8));
  m = fmaxf(m, __shfl_xor(m, 16)); m = fmaxf(m, __shfl_xor(m, 32));
  __shared__ float sm[4];
  if ((threadIdx.x & 63) == 0) sm[threadIdx.x >> 6] = m;
  __syncthreads();
  if (threadIdx.x == 0) fmax[h] = fmaxf(fmaxf(sm[0], sm[1]), fmaxf(sm[2], sm[3]));
}

// ---------------- GEMM: outT[c][i] = sum_k A[c][k]*B[i][k] (bf16 in/out) ----------------
__global__ __launch_bounds__(256) void k_gemm_at(const u16* __restrict__ A_all, const u16* __restrict__ B,
                                                 u16* __restrict__ outT_all, int K){
  const int head = blockIdx.y;
  const u16* A = A_all + (size_t)head * 128 * K;
  u16* outT = outT_all + (size_t)head * 128 * N;
  const int lane = threadIdx.x & 63, w = threadIdx.x >> 6;
  const int r16 = lane & 15, g4 = lane >> 4;
  const size_t ib = (size_t)blockIdx.x * 128 + w * 32;
  f32x4 acc[8][2];
  #pragma unroll
  for (int cg = 0; cg < 8; ++cg){ acc[cg][0] = (f32x4){0,0,0,0}; acc[cg][1] = (f32x4){0,0,0,0}; }
  for (int kk = 0; kk < K; kk += 32){
    bf16x8 b0 = *(const bf16x8*)(B + (ib + r16) * (size_t)K + kk + g4 * 8);
    bf16x8 b1 = *(const bf16x8*)(B + (ib + 16 + r16) * (size_t)K + kk + g4 * 8);
    #pragma unroll
    for (int cg = 0; cg < 8; ++cg){
      bf16x8 a = *(const bf16x8*)(A + (size_t)(cg * 16 + r16) * K + kk + g4 * 8);
      acc[cg][0] = mfma16(a, b0, acc[cg][0]);
      acc[cg][1] = mfma16(a, b1, acc[cg][1]);
    }
  }
  #pragma unroll
  for (int cg = 0; cg < 8; ++cg)
    #pragma unroll
    for (int it = 0; it < 2; ++it)
      #pragma unroll
      for (int q = 0; q < 4; ++q)
        outT[(size_t)(cg * 16 + g4 * 4 + q) * N + ib + it * 16 + r16] = f2bf(acc[cg][it][q]);
}

// ---------------- attention: one wave = (32 rows, j-slice, head); bf16 partials ----------------
template<int S>
__global__ __launch_bounds__(64, 3) void k_attn(
    const unsigned char* __restrict__ pk,
    const u16* __restrict__ whT_all,
    const float* __restrict__ f1_all, const float* __restrict__ f2_all,
    const float* __restrict__ fmax_all,
    u16* __restrict__ part, float* __restrict__ pl)
{
  const int h = blockIdx.z;
  const int s = blockIdx.y;
  const u16* whT = whT_all + (size_t)h * 128 * N;
  const float* f1 = f1_all + (size_t)h * N;
  const float* f2 = f2_all + (size_t)h * N;
  const float fmax = fmax_all[h];
  const int lane = threadIdx.x;
  const int r16 = lane & 15, g4 = lane >> 4;
  const size_t ibase = (size_t)blockIdx.x * 32;
  const int t0 = (s * 128) / S, t1 = ((s + 1) * 128) / S;

  float f1v[2], mrow[2], lsum[2];
  f32x4 acc[2][8];
  #pragma unroll
  for (int rg = 0; rg < 2; ++rg){
    f1v[rg] = f1[ibase + rg * 16 + r16];
    const float v = f1v[rg] + fmax;
    mrow[rg] = fmaxf(v, 0.2f * v);
    lsum[rg] = 0.f;
    #pragma unroll
    for (int ct = 0; ct < 8; ++ct) acc[rg][ct] = (f32x4){0,0,0,0};
  }

  for (int t = t0; t < t1; ++t){
    const int j0 = t * 64;
    float fs[16];
    *(f32x4*)&fs[0]  = *(const f32x4*)(f2 + j0 + g4 * 8);
    *(f32x4*)&fs[4]  = *(const f32x4*)(f2 + j0 + g4 * 8 + 4);
    *(f32x4*)&fs[8]  = *(const f32x4*)(f2 + j0 + 32 + g4 * 8);
    *(f32x4*)&fs[12] = *(const f32x4*)(f2 + j0 + 32 + g4 * 8 + 4);
    unsigned int bits[2][2];
    #pragma unroll
    for (int rg = 0; rg < 2; ++rg){
      const size_t rb = (ibase + rg * 16 + r16) * 1024 + t * 8;
      bits[rg][0] = pk[rb + g4];
      bits[rg][1] = pk[rb + 4 + g4];
    }
    bf16x8 pa[2][2];
    #pragma unroll
    for (int rg = 0; rg < 2; ++rg){
      #pragma unroll
      for (int k2 = 0; k2 < 2; ++k2){
        float pv[8];
        #pragma unroll
        for (int x = 0; x < 8; ++x){
          const float y = f1v[rg] + fs[k2 * 8 + x];
          const float lr = fmaxf(y, 0.2f * y);
          const float p = exp2f(lr - mrow[rg]);
          pv[x] = ((bits[rg][k2] >> x) & 1u) ? p : 0.f;
          lsum[rg] += pv[x];
        }
        union { __hip_bfloat162 h2[4]; bf16x8 v8; } u;
        u.h2[0] = __float22bfloat162_rn(make_float2(pv[0], pv[1]));
        u.h2[1] = __float22bfloat162_rn(make_float2(pv[2], pv[3]));
        u.h2[2] = __float22bfloat162_rn(make_float2(pv[4], pv[5]));
        u.h2[3] = __float22bfloat162_rn(make_float2(pv[6], pv[7]));
        pa[rg][k2] = u.v8;
      }
    }
    #pragma unroll
    for (int k2 = 0; k2 < 2; ++k2){
      #pragma unroll
      for (int ct = 0; ct < 8; ++ct){
        bf16x8 b = *(const bf16x8*)(whT + (size_t)(ct * 16 + r16) * N + j0 + k2 * 32 + g4 * 8);
        acc[0][ct] = mfma16(pa[0][k2], b, acc[0][ct]);
        acc[1][ct] = mfma16(pa[1][k2], b, acc[1][ct]);
      }
    }
  }

  const int plane = h * S + s;
  u16* pp = part + (size_t)plane * (size_t)N * 128;
  #pragma unroll
  for (int rg = 0; rg < 2; ++rg){
    float lv = lsum[rg];
    lv += __shfl_xor(lv, 16); lv += __shfl_xor(lv, 32);
    if (lane < 16) pl[(size_t)plane * N + ibase + rg * 16 + lane] = lv;
    #pragma unroll
    for (int ct = 0; ct < 8; ++ct)
      #pragma unroll
      for (int q = 0; q < 4; ++q)
        pp[(ibase + rg * 16 + g4 * 4 + q) * 128 + ct * 16 + r16] = f2bf(acc[rg][ct][q]);
  }
}

// ---------------- merge partials: sum, normalize, elu, write ----------------
template<int S, bool L2>
__global__ __launch_bounds__(256) void k_attn_merge(
    const u16* __restrict__ part, const float* __restrict__ pl,
    u16* __restrict__ hbf, float* __restrict__ nodeout, u16* __restrict__ comb)
{
  const int h = blockIdx.y;
  const int idx = blockIdx.x * 256 + threadIdx.x;   // over N*32
  const int i = idx >> 5, c4 = (idx & 31) * 4;
  f32x4 a = (f32x4){0,0,0,0};
  float L = 0.f;
  #pragma unroll
  for (int s = 0; s < S; ++s){
    const size_t plane = h * S + s;
    u16x4 v = *(const u16x4*)(part + plane * (size_t)N * 128 + (size_t)i * 128 + c4);
    a[0] += bf2f(v[0]); a[1] += bf2f(v[1]); a[2] += bf2f(v[2]); a[3] += bf2f(v[3]);
    L += pl[plane * (size_t)N + i];
  }
  const float linv = 1.f / L;
  u16x4 hv;
  #pragma unroll
  for (int e = 0; e < 4; ++e){
    float o = a[e] * linv;
    o = (o > 0.f) ? o : (__expf(o) - 1.f);
    a[e] = o;
    hv[e] = f2bf(o);
  }
  if constexpr (!L2){
    *(u16x4*)(hbf + (size_t)i * 256 + h * 128 + c4) = hv;
  } else {
    *(f32x4*)(nodeout + (size_t)i * 128 + c4) = a;
    *(u16x4*)(comb + (size_t)i * 256 + 128 + c4) = hv;
  }
}

// ---------------- row-major GEMM + bias + relu (+optional column-sum) ----------------
template<bool STORE, bool COLSUM>
__global__ __launch_bounds__(256) void k_gemm_row(
    const u16* __restrict__ A, const u16* __restrict__ BT,
    const float* __restrict__ bias,
    u16* __restrict__ out, float* __restrict__ csum,
    int K, int Ntot)
{
  const int lane = threadIdx.x & 63, w = threadIdx.x >> 6;
  const int r16 = lane & 15, g4 = lane >> 4;
  const size_t rbase = (size_t)blockIdx.x * 64 + w * 16;
  const int cbase = blockIdx.y * 128;
  f32x4 acc[8];
  #pragma unroll
  for (int ct = 0; ct < 8; ++ct) acc[ct] = (f32x4){0,0,0,0};
  for (int kk = 0; kk < K; kk += 32){
    bf16x8 af = *(const bf16x8*)(A + (rbase + r16) * (size_t)K + kk + g4 * 8);
    #pragma unroll
    for (int ct = 0; ct < 8; ++ct){
      bf16x8 bfr = *(const bf16x8*)(BT + (size_t)(cbase + ct * 16 + r16) * K + kk + g4 * 8);
      acc[ct] = mfma16(af, bfr, acc[ct]);
    }
  }
  #pragma unroll
  for (int ct = 0; ct < 8; ++ct){
    const float bv = bias[cbase + ct * 16 + r16];
    float sacc = 0.f;
    #pragma unroll
    for (int q = 0; q < 4; ++q){
      float v = acc[ct][q] + bv;
      v = fmaxf(v, 0.f);
      if constexpr (STORE)
        out[(rbase + g4 * 4 + q) * (size_t)Ntot + cbase + ct * 16 + r16] = f2bf(v);
      sacc += v;
    }
    if constexpr (COLSUM){
      sacc += __shfl_xor(sacc, 16); sacc += __shfl_xor(sacc, 32);
      if (lane < 16) atomicAdd(&csum[cbase + ct * 16 + lane], sacc);
    }
  }
}

__global__ void k_final(const float* __restrict__ csum, float* __restrict__ out){
  out[threadIdx.x] = csum[threadIdx.x] * (1.f / 8192.f);
}

// ---------------- host launch ----------------
extern "C" void kernel_launch(void* const* d_in, const int* in_sizes, int n_in,
                              void* d_out, int out_size, void* d_ws, size_t ws_size,
                              hipStream_t stream) {
  const int*   adj = (const int*)d_in[0];
  const float* x   = (const float*)d_in[1];
  const float* Wh  = (const float*)d_in[2];
  const float* ah  = (const float*)d_in[3];
  const float* Wo  = (const float*)d_in[4];
  const float* ao  = (const float*)d_in[5];
  const float* g1  = (const float*)d_in[6];
  const float* b1  = (const float*)d_in[7];
  const float* g2  = (const float*)d_in[8];
  const float* b2  = (const float*)d_in[9];
  float* outp = (float*)d_out;
  char* ws = (char*)d_ws;

  constexpr size_t PK   = 0;          //  8,388,608  packed adj bits
  constexpr size_t PART = 8388608;    // 25,165,824  bf16 partials [12][8192][128]
  constexpr size_t PL   = 33554432;   //    393,216  l partials [12][8192] f32
  constexpr size_t XBF  = 33947648;   //  2,097,152  x bf16
  constexpr size_t WHT1 = 36044800;   //  4,194,304  Wh^T layer1 [2][128][8192]
  constexpr size_t WHT2 = 40239104;   //  2,097,152  Wh^T layer2 [128][8192]
  constexpr size_t HBF  = 42336256;   //  4,194,304  h bf16 [8192][256]
  constexpr size_t COMB = 46530560;   //  4,194,304  combined [8192][256]
  constexpr size_t H1RO = 50724864;   //  4,194,304  readout hidden [8192][256]
  constexpr size_t F1S  = 54919168;   //     65,536  [2][8192] f32 (scaled)
  constexpr size_t F2S  = 54984704;   //     65,536
  constexpr size_t FMAX = 55050240;   //        256
  constexpr size_t CSUM = 55050496;   //        512
  constexpr size_t WTH  = 55051008;   //     65,536  W_heads^T bf16 [2][128][128]
  constexpr size_t WOT  = 55116544;   //     65,536  W_out^T bf16 [128][256]
  constexpr size_t G1T  = 55182080;   //    131,072
  constexpr size_t G2T  = 55313152;   //     65,536
  constexpr size_t WA   = 55378688;   //      4,096  wa1[2][128],wa2[2][128],wao1[256],wao2[256]

  hipMemsetAsync(ws + CSUM, 0, 512, stream);

  k_pack<<<2048, 256, 0, stream>>>(adj, (unsigned long long*)(ws + PK));
  k_x2bf<<<1024, 256, 0, stream>>>(x, (u16*)(ws + XBF), (u16*)(ws + COMB));
  k_transpose<<<dim3(64, 2), 256, 0, stream>>>(Wh, (u16*)(ws + WTH), 128, 128);
  k_transpose<<<dim3(128, 1), 256, 0, stream>>>(Wo, (u16*)(ws + WOT), 256, 128);
  k_transpose<<<dim3(256, 1), 256, 0, stream>>>(g1, (u16*)(ws + G1T), 256, 256);
  k_transpose<<<dim3(128, 1), 256, 0, stream>>>(g2, (u16*)(ws + G2T), 256, 128);
  k_wa<<<3, 256, 0, stream>>>(Wh, ah, Wo, ao, (float*)(ws + WA));

  // layer 1
  k_gemv1<<<dim3(512, 2), 256, 0, stream>>>(x, (const float*)(ws + WA),
                                            (float*)(ws + F1S), (float*)(ws + F2S));
  k_fmax<<<2, 256, 0, stream>>>((const float*)(ws + F2S), (float*)(ws + FMAX));
  k_gemm_at<<<dim3(64, 2), 256, 0, stream>>>((const u16*)(ws + WTH), (const u16*)(ws + XBF),
                                             (u16*)(ws + WHT1), 128);
  k_attn<6><<<dim3(256, 6, 2), 64, 0, stream>>>(
      (const unsigned char*)(ws + PK), (const u16*)(ws + WHT1),
      (const float*)(ws + F1S), (const float*)(ws + F2S), (const float*)(ws + FMAX),
      (u16*)(ws + PART), (float*)(ws + PL));
  k_attn_merge<6, false><<<dim3(1024, 2), 256, 0, stream>>>(
      (const u16*)(ws + PART), (const float*)(ws + PL),
      (u16*)(ws + HBF), nullptr, nullptr);

  // layer 2
  k_gemv2<<<dim3(512, 1), 256, 0, stream>>>((const u16*)(ws + HBF),
      (const float*)(ws + WA) + 512, (const float*)(ws + WA) + 768,
      (float*)(ws + F1S), (float*)(ws + F2S));
  k_fmax<<<1, 256, 0, stream>>>((const float*)(ws + F2S), (float*)(ws + FMAX));
  k_gemm_at<<<dim3(64, 1), 256, 0, stream>>>((const u16*)(ws + WOT), (const u16*)(ws + HBF),
                                             (u16*)(ws + WHT2), 256);
  k_attn<12><<<dim3(256, 12, 1), 64, 0, stream>>>(
      (const unsigned char*)(ws + PK), (const u16*)(ws + WHT2),
      (const float*)(ws + F1S), (const float*)(ws + F2S), (const float*)(ws + FMAX),
      (u16*)(ws + PART), (float*)(ws + PL));
  k_attn_merge<12, true><<<dim3(1024, 1), 256, 0, stream>>>(
      (const u16*)(ws + PART), (const float*)(ws + PL),
      nullptr, outp, (u16*)(ws + COMB));

  // readout MLP
  k_gemm_row<true, false><<<dim3(128, 2), 256, 0, stream>>>(
      (const u16*)(ws + COMB), (const u16*)(ws + G1T), b1,
      (u16*)(ws + H1RO), nullptr, 256, 256);
  k_gemm_row<false, true><<<dim3(128, 1), 256, 0, stream>>>(
      (const u16*)(ws + H1RO), (const u16*)(ws + G2T), b2,
      nullptr, (float*)(ws + CSUM), 256, 128);
  k_final<<<1, 128, 0, stream>>>((const float*)(ws + CSUM), outp + (size_t)N * 128);
}